// Round 3
// baseline (539.440 us; speedup 1.0000x reference)
//
#include <hip/hip_runtime.h>
#include <math.h>

#define NW 100000
#define NS 10000
#define NE 800000
#define DIM 256
#define NH 4
#define DFF 512
#define NEG_SLOPE 0.2f
#define CAP 64   // bucket capacity; deg ~ Poisson(8), P(>64) ~ 0

typedef __attribute__((ext_vector_type(8))) short bf16x8;
typedef __attribute__((ext_vector_type(8))) unsigned short ushortx8;
typedef __attribute__((ext_vector_type(16))) float floatx16;

// ---------------- helpers ----------------
__device__ __forceinline__ unsigned short f2bf(float f) {  // RNE fp32->bf16
    unsigned int u = __float_as_uint(f);
    unsigned int r = (u + 0x7fffu + ((u >> 16) & 1u)) >> 16;
    return (unsigned short)r;
}
__device__ __forceinline__ float bf2f(unsigned short u) {
    return __uint_as_float(((unsigned int)u) << 16);
}
__device__ __forceinline__ void gload_lds16(const void* g, void* l) {
    __builtin_amdgcn_global_load_lds(
        (const __attribute__((address_space(1))) unsigned int*)g,
        (__attribute__((address_space(3))) unsigned int*)l, 16, 0, 0);
}
__device__ __forceinline__ float wave_sum64(float v) {
#pragma unroll
    for (int m = 32; m; m >>= 1) v += __shfl_xor(v, m, 64);
    return v;
}
// packs (lo,hi) -> [15:0]=bf16(lo), [31:16]=bf16(hi), RNE
__device__ __forceinline__ unsigned int cvt_pk_bf16(float lo, float hi) {
    unsigned int d;
    asm("v_cvt_pk_bf16_f32 %0, %1, %2" : "=v"(d) : "v"(lo), "v"(hi));
    return d;
}
// a'[i+32] = b[i]; b'[i] = a[i+32]  (swap a's upper half with b's lower half)
__device__ __forceinline__ void permlane32_swap(unsigned int& a, unsigned int& b) {
    asm("v_permlane32_swap_b32 %0, %1" : "+v"(a), "+v"(b));
}

// ---------------- small kernels ----------------

__global__ void zero_count(int* __restrict__ count) {
    int i = blockIdx.x * 256 + threadIdx.x;
    if (i < NW) count[i] = 0;
}

// C[k,h] = sum_d W[k, h*64+d] * A[h,d]
__global__ void compute_C(const float* __restrict__ W_src, const float* __restrict__ attn_l,
                          const float* __restrict__ W_dst, const float* __restrict__ attn_r,
                          float* __restrict__ C_src, float* __restrict__ C_dst) {
    const float* W = blockIdx.x ? W_dst : W_src;
    const float* A = blockIdx.x ? attn_r : attn_l;
    float* C = blockIdx.x ? C_dst : C_src;
    int k = threadIdx.x;
#pragma unroll
    for (int h = 0; h < NH; h++) {
        const float4* Wv = (const float4*)(W + (size_t)k * DIM + h * 64);
        const float4* Av = (const float4*)(A + h * 64);
        float s = 0.f;
#pragma unroll
        for (int d = 0; d < 16; d++) {
            float4 w = Wv[d], a = Av[d];
            s += w.x * a.x + w.y * a.y + w.z * a.z + w.w * a.w;
        }
        C[k * NH + h] = s;
    }
}

// el[n,h] = sent[n,:] @ C_src[:,h]; one wave per row
__global__ __launch_bounds__(256) void rowdot(const float* __restrict__ X,
                                              const float* __restrict__ C,
                                              float* __restrict__ out, int N) {
    int wave = (blockIdx.x * blockDim.x + threadIdx.x) >> 6;
    int lane = threadIdx.x & 63;
    if (wave >= N) return;
    float4 x = ((const float4*)(X + (size_t)wave * DIM))[lane];
    const float4* Cv = (const float4*)C;
    float4 c0 = Cv[lane * 4 + 0], c1 = Cv[lane * 4 + 1], c2 = Cv[lane * 4 + 2], c3 = Cv[lane * 4 + 3];
    float p0 = x.x * c0.x + x.y * c1.x + x.z * c2.x + x.w * c3.x;
    float p1 = x.x * c0.y + x.y * c1.y + x.z * c2.y + x.w * c3.y;
    float p2 = x.x * c0.z + x.y * c1.z + x.z * c2.z + x.w * c3.z;
    float p3 = x.x * c0.w + x.y * c1.w + x.z * c2.w + x.w * c3.w;
    p0 = wave_sum64(p0); p1 = wave_sum64(p1); p2 = wave_sum64(p2); p3 = wave_sum64(p3);
    if (lane == 0) {
        out[(size_t)wave * NH + 0] = p0; out[(size_t)wave * NH + 1] = p1;
        out[(size_t)wave * NH + 2] = p2; out[(size_t)wave * NH + 3] = p3;
    }
}

// feat16 = bf16(sent @ W_src) : [NS,256]
__global__ __launch_bounds__(256) void feat_gemm(const float* __restrict__ X,
                                                 const float* __restrict__ W,
                                                 unsigned short* __restrict__ out) {
    __shared__ float a[16][DIM];
    int t = threadIdx.x;
    int rg = t >> 6;
    int lane = t & 63;
    int c0 = lane * 4;
    size_t row0 = (size_t)blockIdx.x * 16;
#pragma unroll 4
    for (int i = 0; i < 16; i++) a[i][t] = X[(row0 + i) * DIM + t];
    __syncthreads();
    float acc[4][4] = {};
    for (int kk = 0; kk < DIM; kk += 4) {
        float af[4][4];
#pragma unroll
        for (int i = 0; i < 4; i++) {
            float4 v = *(const float4*)&a[rg * 4 + i][kk];
            af[i][0] = v.x; af[i][1] = v.y; af[i][2] = v.z; af[i][3] = v.w;
        }
        float wf[4][4];
#pragma unroll
        for (int j2 = 0; j2 < 4; j2++) {
            float4 v = *(const float4*)&W[(size_t)(kk + j2) * DIM + c0];
            wf[j2][0] = v.x; wf[j2][1] = v.y; wf[j2][2] = v.z; wf[j2][3] = v.w;
        }
#pragma unroll
        for (int i = 0; i < 4; i++)
#pragma unroll
            for (int j2 = 0; j2 < 4; j2++)
#pragma unroll
                for (int j = 0; j < 4; j++)
                    acc[i][j] = fmaf(af[i][j2], wf[j2][j], acc[i][j]);
    }
#pragma unroll
    for (int i = 0; i < 4; i++) {
        ushort4 p;
        p.x = f2bf(acc[i][0]); p.y = f2bf(acc[i][1]);
        p.z = f2bf(acc[i][2]); p.w = f2bf(acc[i][3]);
        *(ushort4*)&out[(row0 + rg * 4 + i) * DIM + c0] = p;
    }
}

__global__ void scatter_edges(const int* __restrict__ src, const int* __restrict__ dst,
                              int* __restrict__ count, unsigned short* __restrict__ bucket) {
    int e = blockIdx.x * 256 + threadIdx.x;
    if (e >= NE) return;
    int w = dst[e];
    int pos = atomicAdd(&count[w], 1);
    if (pos < CAP) bucket[(size_t)w * CAP + pos] = (unsigned short)src[e];
}

// Fragment-packed weights (bf16), octet layout [k>>3][n][k&7]:
// w1p[(k>>3)*512*8 + n*8 + (k&7)] = w1[k][n]   (k<256, n<512)  -- A-frag of W1^T
// w2p[(k2>>3)*256*8 + c*8 + (k2&7)] = w2[k2][c] (k2<512, c<256) -- B-frag of W2
// Either half-wave's fragment load = 32 lanes x 16B contiguous.
__global__ void prep_weights(const float* __restrict__ w1, const float* __restrict__ w2,
                             unsigned short* __restrict__ w1p, unsigned short* __restrict__ w2p) {
    int b = blockIdx.x, t = threadIdx.x;
    if (b < DFF) {
        int n = b, k = t;   // w1[k][n]
        w1p[((size_t)(k >> 3) * 512 + n) * 8 + (k & 7)] = f2bf(w1[(size_t)k * DFF + n]);
    } else {
        int c = b - DFF;    // w2[k2][c]
#pragma unroll
        for (int kk = 0; kk < 2; kk++) {
            int k2 = t + kk * 256;
            w2p[((size_t)(k2 >> 3) * 256 + c) * 8 + (k2 & 7)] = f2bf(w2[(size_t)k2 * 256 + c]);
        }
    }
}

// ---------------- GAT: 2 nodes per wave, h -> bf16 ----------------
// hbf row n is INTERLEAVED into d_out: bytes [1024n+512, 1024n+1024).
// This makes each FFN block's reads disjoint from all other blocks' writes.
// Softmax: no max subtraction — scores bounded (|e| ~< 6), exp(e)/sum(exp(e))
// is mathematically identical to the max-shifted form.
__global__ __launch_bounds__(256) void gat_h(
    const int* __restrict__ count, const unsigned short* __restrict__ bucket,
    const float* __restrict__ el, const float* __restrict__ Cdst,
    const unsigned short* __restrict__ feat16, const float* __restrict__ word,
    const float* __restrict__ gat_bias, unsigned short* hb)
{
    __shared__ unsigned short sbuf[8][64];
    __shared__ float abuf[8][4][64];
    int tid = threadIdx.x;
    int lane = tid & 63, wv = tid >> 6;
    int hl = lane & 31, half = lane >> 5;
    int nl = wv * 2 + half;                 // node-local 0..7
    int node = blockIdx.x * 8 + nl;
    int deg = count[node]; if (deg > CAP) deg = CAP;

    // word row, cols hl*8 .. hl*8+7
    const float4* wr = (const float4*)(word + (size_t)node * DIM);
    float4 w0 = wr[hl * 2], w1v = wr[hl * 2 + 1];
    float wcol[8] = {w0.x, w0.y, w0.z, w0.w, w1v.x, w1v.y, w1v.z, w1v.w};

    // er inline: p[h] = sum_k word[k] * Cdst[k][h]
    const float4* Cv = (const float4*)Cdst;
    float p0 = 0.f, p1 = 0.f, p2 = 0.f, p3 = 0.f;
#pragma unroll
    for (int j = 0; j < 8; j++) {
        float4 c = Cv[hl * 8 + j];
        float wj = wcol[j];
        p0 = fmaf(wj, c.x, p0); p1 = fmaf(wj, c.y, p1);
        p2 = fmaf(wj, c.z, p2); p3 = fmaf(wj, c.w, p3);
    }
#pragma unroll
    for (int m = 1; m < 32; m <<= 1) {
        p0 += __shfl_xor(p0, m, 64); p1 += __shfl_xor(p1, m, 64);
        p2 += __shfl_xor(p2, m, 64); p3 += __shfl_xor(p3, m, 64);
    }

    // un-normalized exp scores for slots hl and hl+32 (no max pass needed)
    int sa = 0, sb = 0;
    float xa0 = 0.f, xa1 = 0.f, xa2 = 0.f, xa3 = 0.f;
    float xb0 = 0.f, xb1 = 0.f, xb2 = 0.f, xb3 = 0.f;
    if (hl < deg) {
        sa = bucket[(size_t)node * CAP + hl];
        float4 e = ((const float4*)el)[sa];
        float v;
        v = e.x + p0; xa0 = expf(v > 0.f ? v : NEG_SLOPE * v);
        v = e.y + p1; xa1 = expf(v > 0.f ? v : NEG_SLOPE * v);
        v = e.z + p2; xa2 = expf(v > 0.f ? v : NEG_SLOPE * v);
        v = e.w + p3; xa3 = expf(v > 0.f ? v : NEG_SLOPE * v);
    }
    if (hl + 32 < deg) {
        sb = bucket[(size_t)node * CAP + hl + 32];
        float4 e = ((const float4*)el)[sb];
        float v;
        v = e.x + p0; xb0 = expf(v > 0.f ? v : NEG_SLOPE * v);
        v = e.y + p1; xb1 = expf(v > 0.f ? v : NEG_SLOPE * v);
        v = e.z + p2; xb2 = expf(v > 0.f ? v : NEG_SLOPE * v);
        v = e.w + p3; xb3 = expf(v > 0.f ? v : NEG_SLOPE * v);
    }
    float d0 = xa0 + xb0, d1 = xa1 + xb1, d2 = xa2 + xb2, d3 = xa3 + xb3;
#pragma unroll
    for (int m = 1; m < 32; m <<= 1) {
        d0 += __shfl_xor(d0, m, 64); d1 += __shfl_xor(d1, m, 64);
        d2 += __shfl_xor(d2, m, 64); d3 += __shfl_xor(d3, m, 64);
    }
    float i0 = 1.f / d0, i1 = 1.f / d1, i2 = 1.f / d2, i3 = 1.f / d3;
    sbuf[nl][hl] = (unsigned short)sa;
    sbuf[nl][hl + 32] = (unsigned short)sb;
    abuf[nl][0][hl] = xa0 * i0; abuf[nl][0][hl + 32] = xb0 * i0;
    abuf[nl][1][hl] = xa1 * i1; abuf[nl][1][hl + 32] = xb1 * i1;
    abuf[nl][2][hl] = xa2 * i2; abuf[nl][2][hl + 32] = xb2 * i2;
    abuf[nl][3][hl] = xa3 * i3; abuf[nl][3][hl + 32] = xb3 * i3;
    __syncthreads();

    // gather: lane covers 8 cols, head hh = hl>>3
    int hh = hl >> 3;
    float acc[8] = {};
    for (int i = 0; i < deg; i++) {
        int si = sbuf[nl][i];
        float aa = abuf[nl][hh][i];
        ushortx8 f = *(const ushortx8*)&feat16[(size_t)si * DIM + hl * 8];
#pragma unroll
        for (int j = 0; j < 8; j++) acc[j] = fmaf(aa, bf2f(f[j]), acc[j]);
    }
    float4 g0 = ((const float4*)gat_bias)[hl * 2], g1 = ((const float4*)gat_bias)[hl * 2 + 1];
    float gb[8] = {g0.x, g0.y, g0.z, g0.w, g1.x, g1.y, g1.z, g1.w};
    ushortx8 o;
#pragma unroll
    for (int j = 0; j < 8; j++) {
        float r = acc[j] + gb[j];
        r = r > 0.f ? r : (expf(r) - 1.f);
        o[j] = f2bf(wcol[j] + r);
    }
    // interleaved hbf: row stride 512 ushorts, offset 256
    *(ushortx8*)&hb[(size_t)node * 512 + 256 + hl * 8] = o;
}

// ---------------- Fused FFN, barrier-free K-chain ----------------
// out = relu(h@W1+b1)@W2 + b2.  BM=128 rows/block, 4 waves; each wave owns 32
// rows x all 256 out cols (8 C-tiles, accumulated in registers).
// Per 32-hid block hb (16 total), straight-line, NO barriers:
//   GEMM1 swapped:  Pt = mfma(A=W1^T-frag(global), B=H^T-frag(LDS)) -> lane=row
//   bias+relu in regs, v_cvt_pk_bf16_f32 pairs, 4x v_permlane32_swap_b32
//     assembles GEMM2 A-frags fully in-register (HK T12 pattern)
//   GEMM2: oacc[ct] += mfma(P-frag, W2-frag(global))
// Only barrier: after initial As staging.  Weight frags stream from L1/L2
// (all 4 waves read the same sequence).
__global__ __launch_bounds__(256, 2) void ffn_fused2(
    const unsigned short* hb,                // = (ushort*)d_out (aliases out!)
    const unsigned short* __restrict__ w1p,
    const float* __restrict__ b1,
    const unsigned short* __restrict__ w2p,
    const float* __restrict__ b2,
    float* out)
{
    __shared__ unsigned short As[4][128][64];  // 64 KB, granule-XOR swizzled
    int tid = threadIdx.x;
    int lane = tid & 63, wv = tid >> 6;
    int l31 = lane & 31, half = lane >> 5;
    int row0 = blockIdx.x * 128;
    const bf16x8* w1v = (const bf16x8*)w1p;
    const bf16x8* w2v = (const bf16x8*)w2p;

    // stage A = hb rows row0..row0+127 (K=256); slot s of row r holds granule s^(r&7)
#pragma unroll
    for (int kc = 0; kc < 4; kc++) {
#pragma unroll
        for (int it = 0; it < 4; it++) {
            int rbase = wv * 32 + it * 8;
            int r = rbase + (lane >> 3);
            int rl = row0 + r; rl = rl < NW ? rl : NW - 1;
            int glf = (lane & 7) ^ (r & 7);
            gload_lds16(hb + (size_t)rl * 512 + 256 + kc * 64 + glf * 8, &As[kc][rbase][0]);
        }
    }

    floatx16 oacc[8];
#pragma unroll
    for (int j = 0; j < 8; j++) oacc[j] = (floatx16)(0.f);
    int m = wv * 32 + l31;        // this lane's H row (B-operand col in swapped G1)
    __syncthreads();

    for (int hbi = 0; hbi < 16; hbi++) {
        // ---- GEMM1 swapped: Pt[hid][row] for hid block hbi, this wave's 32 rows ----
        floatx16 hacc = (floatx16)(0.f);
#pragma unroll
        for (int ks = 0; ks < 16; ks++) {
            bf16x8 afrag = w1v[(ks * 2 + half) * 512 + hbi * 32 + l31];   // W1^T
            int g = (ks & 3) * 2 + half;
            bf16x8 bfrag = *(const bf16x8*)&As[ks >> 2][m][((g ^ (m & 7)) & 7) * 8];  // H^T
            hacc = __builtin_amdgcn_mfma_f32_32x32x16_bf16(afrag, bfrag, hacc, 0, 0, 0);
        }
        // ---- bias + relu in registers; reg j holds hid = (j&3)+8*(j>>2)+4*half ----
        const float* b1b = b1 + hbi * 32 + 4 * half;
        float4 bb0 = *(const float4*)(b1b + 0);
        float4 bb1 = *(const float4*)(b1b + 8);
        float4 bb2 = *(const float4*)(b1b + 16);
        float4 bb3 = *(const float4*)(b1b + 24);
        float bs[16] = {bb0.x, bb0.y, bb0.z, bb0.w, bb1.x, bb1.y, bb1.z, bb1.w,
                        bb2.x, bb2.y, bb2.z, bb2.w, bb3.x, bb3.y, bb3.z, bb3.w};
        float p[16];
#pragma unroll
        for (int j = 0; j < 16; j++) {
            float v = hacc[j] + bs[j];
            p[j] = v > 0.f ? v : 0.f;
        }
        // ---- pack to bf16 + half-exchange -> GEMM2 A-frags (in-register) ----
        unsigned int pk0 = cvt_pk_bf16(p[0], p[1]),  pk1 = cvt_pk_bf16(p[2], p[3]);
        unsigned int pk2 = cvt_pk_bf16(p[4], p[5]),  pk3 = cvt_pk_bf16(p[6], p[7]);
        unsigned int pk4 = cvt_pk_bf16(p[8], p[9]),  pk5 = cvt_pk_bf16(p[10], p[11]);
        unsigned int pk6 = cvt_pk_bf16(p[12], p[13]), pk7 = cvt_pk_bf16(p[14], p[15]);
        permlane32_swap(pk0, pk2);   // pk0: k(0,1)|(8,9)   pk2: k(4,5)|(12,13)
        permlane32_swap(pk1, pk3);   // pk1: k(2,3)|(10,11) pk3: k(6,7)|(14,15)
        permlane32_swap(pk4, pk6);
        permlane32_swap(pk5, pk7);
        union { unsigned int u[4]; bf16x8 v; } f0, f1;
        f0.u[0] = pk0; f0.u[1] = pk1; f0.u[2] = pk2; f0.u[3] = pk3;  // hid 0..15
        f1.u[0] = pk4; f1.u[1] = pk5; f1.u[2] = pk6; f1.u[3] = pk7;  // hid 16..31
        // ---- GEMM2: oacc[ct] += P-frag @ W2-frag ----
#pragma unroll
        for (int ks2 = 0; ks2 < 2; ks2++) {
            bf16x8 pa = ks2 ? f1.v : f0.v;
#pragma unroll
            for (int ct = 0; ct < 8; ct++) {
                bf16x8 bfr = w2v[(hbi * 4 + ks2 * 2 + half) * 256 + ct * 32 + l31];
                oacc[ct] = __builtin_amdgcn_mfma_f32_32x32x16_bf16(pa, bfr, oacc[ct], 0, 0, 0);
            }
        }
    }
    // ---- epilogue: + b2, fp32 stores (lane=col -> coalesced 128B segments) ----
#pragma unroll
    for (int ct = 0; ct < 8; ct++) {
        int c = ct * 32 + l31;
        float bias = b2[c];
#pragma unroll
        for (int reg = 0; reg < 16; reg++) {
            int rloc = row0 + wv * 32 + (reg & 3) + 8 * (reg >> 2) + 4 * half;
            if (rloc < NW) out[(size_t)rloc * DIM + c] = oacc[ct][reg] + bias;
        }
    }
}

// ---------------- launch ----------------
extern "C" void kernel_launch(void* const* d_in, const int* in_sizes, int n_in,
                              void* d_out, int out_size, void* d_ws, size_t ws_size,
                              hipStream_t stream) {
    const float* word   = (const float*)d_in[0];
    const float* sent   = (const float*)d_in[1];
    const int*   src    = (const int*)d_in[2];
    const int*   dst    = (const int*)d_in[3];
    const float* W_src  = (const float*)d_in[4];
    const float* W_dst  = (const float*)d_in[5];
    const float* attn_l = (const float*)d_in[6];
    const float* attn_r = (const float*)d_in[7];
    const float* gbias  = (const float*)d_in[8];
    const float* w1     = (const float*)d_in[9];
    const float* b1     = (const float*)d_in[10];
    const float* w2     = (const float*)d_in[11];
    const float* b2     = (const float*)d_in[12];
    float* out = (float*)d_out;
    // hbf row n interleaved into d_out bytes [1024n+512, 1024n+1024)
    unsigned short* hb = (unsigned short*)d_out;

    char* wsb = (char*)d_ws;
    unsigned short* w1p = (unsigned short*)wsb;                 // 512*256
    unsigned short* w2p = w1p + (size_t)DFF * 256;              // 256*512
    float* el    = (float*)(w2p + (size_t)256 * DFF);           // NS*4
    float* C_src = el + (size_t)NS * NH;
    float* C_dst = C_src + DIM * NH;
    unsigned short* feat16 = (unsigned short*)(C_dst + DIM * NH);  // NS*256
    int* count = (int*)(feat16 + (size_t)NS * DIM);             // NW
    unsigned short* bucket = (unsigned short*)(count + NW);     // NW*CAP

    hipLaunchKernelGGL(zero_count, dim3((NW + 255) / 256), dim3(256), 0, stream, count);
    hipLaunchKernelGGL(compute_C, dim3(2), dim3(256), 0, stream,
                       W_src, attn_l, W_dst, attn_r, C_src, C_dst);
    hipLaunchKernelGGL(prep_weights, dim3(DFF + 256), dim3(256), 0, stream, w1, w2, w1p, w2p);
    hipLaunchKernelGGL(rowdot, dim3(NS / 4), dim3(256), 0, stream, sent, C_src, el, NS);
    hipLaunchKernelGGL(feat_gemm, dim3(NS / 16), dim3(256), 0, stream, sent, W_src, feat16);
    hipLaunchKernelGGL(scatter_edges, dim3(NE / 256), dim3(256), 0, stream, src, dst, count, bucket);
    hipLaunchKernelGGL(gat_h, dim3(NW / 8), dim3(256), 0, stream,
                       count, bucket, el, C_dst, feat16, word, gbias, hb);
    hipLaunchKernelGGL(ffn_fused2, dim3((NW + 127) / 128), dim3(256), 0, stream,
                       hb, w1p, b1, w2p, b2, out);
}

// Round 4
// 444.099 us; speedup vs baseline: 1.2147x; 1.2147x over previous
//
#include <hip/hip_runtime.h>
#include <math.h>

#define NW 100000
#define NS 10000
#define NE 800000
#define DIM 256
#define NH 4
#define DFF 512
#define NEG_SLOPE 0.2f
#define CAP 64   // bucket capacity; deg ~ Poisson(8), P(>64) ~ 0

#define NZB 391          // ceil(NW/256) zero blocks
#define FG_B 625         // feat_gemm blocks (NS/16)
#define RD_B 2500        // rowdot blocks (NS/4)
#define SC_B 3125        // scatter blocks (NE/256)

typedef __attribute__((ext_vector_type(8))) short bf16x8;
typedef __attribute__((ext_vector_type(8))) unsigned short ushortx8;
typedef __attribute__((ext_vector_type(16))) float floatx16;

// ---------------- helpers ----------------
__device__ __forceinline__ unsigned short f2bf(float f) {  // RNE fp32->bf16
    unsigned int u = __float_as_uint(f);
    unsigned int r = (u + 0x7fffu + ((u >> 16) & 1u)) >> 16;
    return (unsigned short)r;
}
__device__ __forceinline__ float bf2f(unsigned short u) {
    return __uint_as_float(((unsigned int)u) << 16);
}
__device__ __forceinline__ void gload_lds16(const void* g, void* l) {
    __builtin_amdgcn_global_load_lds(
        (const __attribute__((address_space(1))) unsigned int*)g,
        (__attribute__((address_space(3))) unsigned int*)l, 16, 0, 0);
}
__device__ __forceinline__ float wave_sum64(float v) {
#pragma unroll
    for (int m = 32; m; m >>= 1) v += __shfl_xor(v, m, 64);
    return v;
}
// packs (lo,hi) -> [15:0]=bf16(lo), [31:16]=bf16(hi), RNE
__device__ __forceinline__ unsigned int cvt_pk_bf16(float lo, float hi) {
    unsigned int d;
    asm("v_cvt_pk_bf16_f32 %0, %1, %2" : "=v"(d) : "v"(lo), "v"(hi));
    return d;
}
// a'[i+32] = b[i]; b'[i] = a[i+32]
__device__ __forceinline__ void permlane32_swap(unsigned int& a, unsigned int& b) {
    asm("v_permlane32_swap_b32 %0, %1" : "+v"(a), "+v"(b));
}

// ---------------- merged prep kernel 1 ----------------
// blocks: [0,391) zero_count | [391,393) compute_C | [393,1161) prep_weights
//         [1161,1786) feat_gemm.  All parts mutually independent.
__global__ __launch_bounds__(256) void prep_all(
    const float* __restrict__ sent, const float* __restrict__ W_src,
    const float* __restrict__ attn_l, const float* __restrict__ W_dst,
    const float* __restrict__ attn_r, const float* __restrict__ w1,
    const float* __restrict__ w2,
    float* __restrict__ C_src, float* __restrict__ C_dst,
    unsigned short* __restrict__ w1p, unsigned short* __restrict__ w2p,
    int* __restrict__ count, unsigned short* __restrict__ feat16)
{
    int b = blockIdx.x, t = threadIdx.x;
    if (b < NZB) {
        int i = b * 256 + t;
        if (i < NW) count[i] = 0;
    } else if (b < NZB + 2) {
        // C[k,h] = sum_d W[k, h*64+d] * A[h,d]
        int sel = b - NZB;
        const float* W = sel ? W_dst : W_src;
        const float* A = sel ? attn_r : attn_l;
        float* C = sel ? C_dst : C_src;
        int k = t;
#pragma unroll
        for (int h = 0; h < NH; h++) {
            const float4* Wv = (const float4*)(W + (size_t)k * DIM + h * 64);
            const float4* Av = (const float4*)(A + h * 64);
            float s = 0.f;
#pragma unroll
            for (int d = 0; d < 16; d++) {
                float4 w = Wv[d], a = Av[d];
                s += w.x * a.x + w.y * a.y + w.z * a.z + w.w * a.w;
            }
            C[k * NH + h] = s;
        }
    } else if (b < NZB + 2 + DFF + 256) {
        // fragment-packed weights, octet layout [k>>3][n][k&7]
        int bb = b - (NZB + 2);
        if (bb < DFF) {
            int n = bb, k = t;   // w1[k][n]
            w1p[((size_t)(k >> 3) * 512 + n) * 8 + (k & 7)] = f2bf(w1[(size_t)k * DFF + n]);
        } else {
            int c = bb - DFF;    // w2[k2][c]
#pragma unroll
            for (int kk = 0; kk < 2; kk++) {
                int k2 = t + kk * 256;
                w2p[((size_t)(k2 >> 3) * 256 + c) * 8 + (k2 & 7)] = f2bf(w2[(size_t)k2 * 256 + c]);
            }
        }
    } else {
        // feat16 = bf16(sent @ W_src)
        __shared__ float a[16][DIM];
        int rg = t >> 6;
        int lane = t & 63;
        int c0 = lane * 4;
        size_t row0 = (size_t)(b - (NZB + 2 + DFF + 256)) * 16;
#pragma unroll 4
        for (int i = 0; i < 16; i++) a[i][t] = sent[(row0 + i) * DIM + t];
        __syncthreads();
        float acc[4][4] = {};
        for (int kk = 0; kk < DIM; kk += 4) {
            float af[4][4];
#pragma unroll
            for (int i = 0; i < 4; i++) {
                float4 v = *(const float4*)&a[rg * 4 + i][kk];
                af[i][0] = v.x; af[i][1] = v.y; af[i][2] = v.z; af[i][3] = v.w;
            }
            float wf[4][4];
#pragma unroll
            for (int j2 = 0; j2 < 4; j2++) {
                float4 v = *(const float4*)&W_src[(size_t)(kk + j2) * DIM + c0];
                wf[j2][0] = v.x; wf[j2][1] = v.y; wf[j2][2] = v.z; wf[j2][3] = v.w;
            }
#pragma unroll
            for (int i = 0; i < 4; i++)
#pragma unroll
                for (int j2 = 0; j2 < 4; j2++)
#pragma unroll
                    for (int j = 0; j < 4; j++)
                        acc[i][j] = fmaf(af[i][j2], wf[j2][j], acc[i][j]);
        }
#pragma unroll
        for (int i = 0; i < 4; i++) {
            ushort4 p;
            p.x = f2bf(acc[i][0]); p.y = f2bf(acc[i][1]);
            p.z = f2bf(acc[i][2]); p.w = f2bf(acc[i][3]);
            *(ushort4*)&feat16[(row0 + rg * 4 + i) * DIM + c0] = p;
        }
    }
}

// ---------------- merged prep kernel 2 ----------------
// blocks: [0,2500) rowdot (el) | [2500,5625) scatter_edges
__global__ __launch_bounds__(256) void edge_prep(
    const float* __restrict__ sent, const float* __restrict__ C_src,
    float* __restrict__ el,
    const int* __restrict__ src, const int* __restrict__ dst,
    int* __restrict__ count, unsigned short* __restrict__ bucket)
{
    int b = blockIdx.x, t = threadIdx.x;
    if (b < RD_B) {
        int wave = b * 4 + (t >> 6);
        int lane = t & 63;
        float4 x = ((const float4*)(sent + (size_t)wave * DIM))[lane];
        const float4* Cv = (const float4*)C_src;
        float4 c0 = Cv[lane * 4 + 0], c1 = Cv[lane * 4 + 1], c2 = Cv[lane * 4 + 2], c3 = Cv[lane * 4 + 3];
        float p0 = x.x * c0.x + x.y * c1.x + x.z * c2.x + x.w * c3.x;
        float p1 = x.x * c0.y + x.y * c1.y + x.z * c2.y + x.w * c3.y;
        float p2 = x.x * c0.z + x.y * c1.z + x.z * c2.z + x.w * c3.z;
        float p3 = x.x * c0.w + x.y * c1.w + x.z * c2.w + x.w * c3.w;
        p0 = wave_sum64(p0); p1 = wave_sum64(p1); p2 = wave_sum64(p2); p3 = wave_sum64(p3);
        if (lane == 0) {
            el[(size_t)wave * NH + 0] = p0; el[(size_t)wave * NH + 1] = p1;
            el[(size_t)wave * NH + 2] = p2; el[(size_t)wave * NH + 3] = p3;
        }
    } else {
        int e = (b - RD_B) * 256 + t;
        if (e < NE) {
            int w = dst[e];
            int pos = atomicAdd(&count[w], 1);
            if (pos < CAP) bucket[(size_t)w * CAP + pos] = (unsigned short)src[e];
        }
    }
}

// ---------------- GAT: 2 nodes per wave, h -> bf16 ----------------
// hbf row n INTERLEAVED into d_out: bytes [1024n+512, 1024n+1024).
__global__ __launch_bounds__(256) void gat_h(
    const int* __restrict__ count, const unsigned short* __restrict__ bucket,
    const float* __restrict__ el, const float* __restrict__ Cdst,
    const unsigned short* __restrict__ feat16, const float* __restrict__ word,
    const float* __restrict__ gat_bias, unsigned short* hb)
{
    __shared__ unsigned short sbuf[8][64];
    __shared__ float abuf[8][4][64];
    int tid = threadIdx.x;
    int lane = tid & 63, wv = tid >> 6;
    int hl = lane & 31, half = lane >> 5;
    int nl = wv * 2 + half;                 // node-local 0..7
    int node = blockIdx.x * 8 + nl;
    int deg = count[node]; if (deg > CAP) deg = CAP;

    const float4* wr = (const float4*)(word + (size_t)node * DIM);
    float4 w0 = wr[hl * 2], w1v = wr[hl * 2 + 1];
    float wcol[8] = {w0.x, w0.y, w0.z, w0.w, w1v.x, w1v.y, w1v.z, w1v.w};

    const float4* Cv = (const float4*)Cdst;
    float p0 = 0.f, p1 = 0.f, p2 = 0.f, p3 = 0.f;
#pragma unroll
    for (int j = 0; j < 8; j++) {
        float4 c = Cv[hl * 8 + j];
        float wj = wcol[j];
        p0 = fmaf(wj, c.x, p0); p1 = fmaf(wj, c.y, p1);
        p2 = fmaf(wj, c.z, p2); p3 = fmaf(wj, c.w, p3);
    }
#pragma unroll
    for (int m = 1; m < 32; m <<= 1) {
        p0 += __shfl_xor(p0, m, 64); p1 += __shfl_xor(p1, m, 64);
        p2 += __shfl_xor(p2, m, 64); p3 += __shfl_xor(p3, m, 64);
    }

    int sa = 0, sb = 0;
    float xa0 = 0.f, xa1 = 0.f, xa2 = 0.f, xa3 = 0.f;
    float xb0 = 0.f, xb1 = 0.f, xb2 = 0.f, xb3 = 0.f;
    if (hl < deg) {
        sa = bucket[(size_t)node * CAP + hl];
        float4 e = ((const float4*)el)[sa];
        float v;
        v = e.x + p0; xa0 = expf(v > 0.f ? v : NEG_SLOPE * v);
        v = e.y + p1; xa1 = expf(v > 0.f ? v : NEG_SLOPE * v);
        v = e.z + p2; xa2 = expf(v > 0.f ? v : NEG_SLOPE * v);
        v = e.w + p3; xa3 = expf(v > 0.f ? v : NEG_SLOPE * v);
    }
    if (hl + 32 < deg) {
        sb = bucket[(size_t)node * CAP + hl + 32];
        float4 e = ((const float4*)el)[sb];
        float v;
        v = e.x + p0; xb0 = expf(v > 0.f ? v : NEG_SLOPE * v);
        v = e.y + p1; xb1 = expf(v > 0.f ? v : NEG_SLOPE * v);
        v = e.z + p2; xb2 = expf(v > 0.f ? v : NEG_SLOPE * v);
        v = e.w + p3; xb3 = expf(v > 0.f ? v : NEG_SLOPE * v);
    }
    float d0 = xa0 + xb0, d1 = xa1 + xb1, d2 = xa2 + xb2, d3 = xa3 + xb3;
#pragma unroll
    for (int m = 1; m < 32; m <<= 1) {
        d0 += __shfl_xor(d0, m, 64); d1 += __shfl_xor(d1, m, 64);
        d2 += __shfl_xor(d2, m, 64); d3 += __shfl_xor(d3, m, 64);
    }
    float i0 = 1.f / d0, i1 = 1.f / d1, i2 = 1.f / d2, i3 = 1.f / d3;
    sbuf[nl][hl] = (unsigned short)sa;
    sbuf[nl][hl + 32] = (unsigned short)sb;
    abuf[nl][0][hl] = xa0 * i0; abuf[nl][0][hl + 32] = xb0 * i0;
    abuf[nl][1][hl] = xa1 * i1; abuf[nl][1][hl + 32] = xb1 * i1;
    abuf[nl][2][hl] = xa2 * i2; abuf[nl][2][hl + 32] = xb2 * i2;
    abuf[nl][3][hl] = xa3 * i3; abuf[nl][3][hl + 32] = xb3 * i3;
    __syncthreads();

    int hh = hl >> 3;
    float acc[8] = {};
    for (int i = 0; i < deg; i++) {
        int si = sbuf[nl][i];
        float aa = abuf[nl][hh][i];
        ushortx8 f = *(const ushortx8*)&feat16[(size_t)si * DIM + hl * 8];
#pragma unroll
        for (int j = 0; j < 8; j++) acc[j] = fmaf(aa, bf2f(f[j]), acc[j]);
    }
    float4 g0 = ((const float4*)gat_bias)[hl * 2], g1 = ((const float4*)gat_bias)[hl * 2 + 1];
    float gb[8] = {g0.x, g0.y, g0.z, g0.w, g1.x, g1.y, g1.z, g1.w};
    ushortx8 o;
#pragma unroll
    for (int j = 0; j < 8; j++) {
        float r = acc[j] + gb[j];
        r = r > 0.f ? r : (expf(r) - 1.f);
        o[j] = f2bf(wcol[j] + r);
    }
    *(ushortx8*)&hb[(size_t)node * 512 + 256 + hl * 8] = o;
}

// ---------------- Fused FFN v3: H in regs, weights LDS-double-buffered ----
// BM=256 rows, 512 threads (8 waves), each wave owns 32 rows x 256 out cols.
// H (this wave's 32 rows x K=256) loaded ONCE to registers (64 VGPR) ->
// GEMM1's B operand is free.  Per 32-hid chunk (16 chunks):
//   W1 slice (256x32) + W2 slice (32x256) = 32 KB staged to LDS via
//   global_load_lds, double-buffered, issued one chunk ahead (T3 2-phase).
//   G1 swapped: hacc = mfma(W1frag(LDS), Hfrag(reg)) -> lane=row
//   bias+relu in regs, cvt_pk+permlane32_swap -> G2 A-frags in-register
//   G2: oacc[ct] += mfma(Pfrag(reg), W2frag(LDS))
// Fresh operand per MFMA = 1KB from LDS only (reg side free) -> feed-bound
// at ~4-6cyc/MFMA instead of the ~12-17% global-feed wall of r1-r3.
__global__ __launch_bounds__(512, 2) void ffn_fused3(
    const unsigned short* hb,                // = (ushort*)d_out (aliases out!)
    const unsigned short* __restrict__ w1p,
    const float* __restrict__ b1,
    const unsigned short* __restrict__ w2p,
    const float* __restrict__ b2,
    float* out)
{
    __shared__ unsigned short W1s[2][8192];  // [buf][1024 octets] = 16 KB each
    __shared__ unsigned short W2s[2][8192];
    int tid = threadIdx.x;
    int lane = tid & 63, wv = tid >> 6;
    int l31 = lane & 31, half = lane >> 5;
    int row0 = blockIdx.x * 256;

    // ---- H rows -> registers (row stride 1024B; each lane consumes full lines) ----
    int myrow = row0 + wv * 32 + l31;
    if (myrow >= NW) myrow = NW - 1;
    const unsigned short* hrow = hb + (size_t)myrow * 512 + 256 + half * 8;
    bf16x8 hreg[16];
#pragma unroll
    for (int ks = 0; ks < 16; ks++)
        hreg[ks] = *(const bf16x8*)(hrow + ks * 16);

    // ---- stage chunk 0 ----
    {
        if (wv < 4) {
#pragma unroll
            for (int it = 0; it < 4; it++) {
                int q = wv * 4 + it;
                const unsigned short* s =
                    w1p + ((size_t)(q * 2 + (lane >> 5)) * 512 + (lane & 31)) * 8;
                gload_lds16(s, &W1s[0][q * 512]);
            }
        } else {
#pragma unroll
            for (int it = 0; it < 4; it++) {
                int qq = (wv - 4) * 4 + it;
                const unsigned short* s = w2p + ((size_t)qq * 64 + lane) * 8;
                gload_lds16(s, &W2s[0][qq * 512]);
            }
        }
    }

    floatx16 oacc[8];
#pragma unroll
    for (int j = 0; j < 8; j++) oacc[j] = (floatx16)(0.f);
    __syncthreads();

#pragma unroll 2
    for (int hbi = 0; hbi < 16; hbi++) {
        int cur = hbi & 1;
        // ---- stage next chunk into buf^1 (overlaps this chunk's compute) ----
        if (hbi < 15) {
            int c = hbi + 1, nb = cur ^ 1;
            if (wv < 4) {
#pragma unroll
                for (int it = 0; it < 4; it++) {
                    int q = wv * 4 + it;
                    const unsigned short* s =
                        w1p + ((size_t)(q * 2 + (lane >> 5)) * 512 + c * 32 + (lane & 31)) * 8;
                    gload_lds16(s, &W1s[nb][q * 512]);
                }
            } else {
#pragma unroll
                for (int it = 0; it < 4; it++) {
                    int qq = (wv - 4) * 4 + it;
                    const unsigned short* s = w2p + ((size_t)c * 1024 + qq * 64 + lane) * 8;
                    gload_lds16(s, &W2s[nb][qq * 512]);
                }
            }
        }
        // ---- G1 swapped: hacc = W1^T-chunk @ H^T ----
        const bf16x8* W1v = (const bf16x8*)W1s[cur];
        floatx16 hacc = (floatx16)(0.f);
#pragma unroll
        for (int ks = 0; ks < 16; ks++) {
            bf16x8 afrag = W1v[(ks * 2 + half) * 32 + l31];
            hacc = __builtin_amdgcn_mfma_f32_32x32x16_bf16(afrag, hreg[ks], hacc, 0, 0, 0);
        }
        // ---- bias + relu; reg j holds hid = (j&3)+8*(j>>2)+4*half ----
        const float* b1b = b1 + hbi * 32 + 4 * half;
        float4 bb0 = *(const float4*)(b1b + 0);
        float4 bb1 = *(const float4*)(b1b + 8);
        float4 bb2 = *(const float4*)(b1b + 16);
        float4 bb3 = *(const float4*)(b1b + 24);
        float bs[16] = {bb0.x, bb0.y, bb0.z, bb0.w, bb1.x, bb1.y, bb1.z, bb1.w,
                        bb2.x, bb2.y, bb2.z, bb2.w, bb3.x, bb3.y, bb3.z, bb3.w};
        float p[16];
#pragma unroll
        for (int j = 0; j < 16; j++) {
            float v = hacc[j] + bs[j];
            p[j] = v > 0.f ? v : 0.f;
        }
        // ---- pack to bf16 + half-exchange -> G2 A-frags in-register ----
        unsigned int pk0 = cvt_pk_bf16(p[0], p[1]),   pk1 = cvt_pk_bf16(p[2], p[3]);
        unsigned int pk2 = cvt_pk_bf16(p[4], p[5]),   pk3 = cvt_pk_bf16(p[6], p[7]);
        unsigned int pk4 = cvt_pk_bf16(p[8], p[9]),   pk5 = cvt_pk_bf16(p[10], p[11]);
        unsigned int pk6 = cvt_pk_bf16(p[12], p[13]), pk7 = cvt_pk_bf16(p[14], p[15]);
        permlane32_swap(pk0, pk2);
        permlane32_swap(pk1, pk3);
        permlane32_swap(pk4, pk6);
        permlane32_swap(pk5, pk7);
        union { unsigned int u[4]; bf16x8 v; } f0, f1;
        f0.u[0] = pk0; f0.u[1] = pk1; f0.u[2] = pk2; f0.u[3] = pk3;  // hid 0..15
        f1.u[0] = pk4; f1.u[1] = pk5; f1.u[2] = pk6; f1.u[3] = pk7;  // hid 16..31
        // ---- G2: oacc[ct] += P-frag @ W2-frag(LDS) ----
        const bf16x8* W2v = (const bf16x8*)W2s[cur];
#pragma unroll
        for (int ks2 = 0; ks2 < 2; ks2++) {
            bf16x8 pa = ks2 ? f1.v : f0.v;
#pragma unroll
            for (int ct = 0; ct < 8; ct++) {
                bf16x8 bfr = W2v[(ks2 * 2 + half) * 256 + ct * 32 + l31];
                oacc[ct] = __builtin_amdgcn_mfma_f32_32x32x16_bf16(pa, bfr, oacc[ct], 0, 0, 0);
            }
        }
        if (hbi < 15) __syncthreads();
    }
    // ---- epilogue: + b2, fp32 stores ----
#pragma unroll
    for (int ct = 0; ct < 8; ct++) {
        int c = ct * 32 + l31;
        float bias = b2[c];
#pragma unroll
        for (int reg = 0; reg < 16; reg++) {
            int rloc = row0 + wv * 32 + (reg & 3) + 8 * (reg >> 2) + 4 * half;
            if (rloc < NW) out[(size_t)rloc * DIM + c] = oacc[ct][reg] + bias;
        }
    }
}

// ---------------- launch ----------------
extern "C" void kernel_launch(void* const* d_in, const int* in_sizes, int n_in,
                              void* d_out, int out_size, void* d_ws, size_t ws_size,
                              hipStream_t stream) {
    const float* word   = (const float*)d_in[0];
    const float* sent   = (const float*)d_in[1];
    const int*   src    = (const int*)d_in[2];
    const int*   dst    = (const int*)d_in[3];
    const float* W_src  = (const float*)d_in[4];
    const float* W_dst  = (const float*)d_in[5];
    const float* attn_l = (const float*)d_in[6];
    const float* attn_r = (const float*)d_in[7];
    const float* gbias  = (const float*)d_in[8];
    const float* w1     = (const float*)d_in[9];
    const float* b1     = (const float*)d_in[10];
    const float* w2     = (const float*)d_in[11];
    const float* b2     = (const float*)d_in[12];
    float* out = (float*)d_out;
    // hbf row n interleaved into d_out bytes [1024n+512, 1024n+1024)
    unsigned short* hb = (unsigned short*)d_out;

    char* wsb = (char*)d_ws;
    unsigned short* w1p = (unsigned short*)wsb;                 // 512*256
    unsigned short* w2p = w1p + (size_t)DFF * 256;              // 256*512
    float* el    = (float*)(w2p + (size_t)256 * DFF);           // NS*4
    float* C_src = el + (size_t)NS * NH;
    float* C_dst = C_src + DIM * NH;
    unsigned short* feat16 = (unsigned short*)(C_dst + DIM * NH);  // NS*256
    int* count = (int*)(feat16 + (size_t)NS * DIM);             // NW
    unsigned short* bucket = (unsigned short*)(count + NW);     // NW*CAP

    hipLaunchKernelGGL(prep_all, dim3(NZB + 2 + DFF + 256 + FG_B), dim3(256), 0, stream,
                       sent, W_src, attn_l, W_dst, attn_r, w1, w2,
                       C_src, C_dst, w1p, w2p, count, feat16);
    hipLaunchKernelGGL(edge_prep, dim3(RD_B + SC_B), dim3(256), 0, stream,
                       sent, C_src, el, src, dst, count, bucket);
    hipLaunchKernelGGL(gat_h, dim3(NW / 8), dim3(256), 0, stream,
                       count, bucket, el, C_dst, feat16, word, gbias, hb);
    hipLaunchKernelGGL(ffn_fused3, dim3(391), dim3(512), 0, stream,
                       hb, w1p, b1, w2p, b2, out);
}